// Round 2
// baseline (222.641 us; speedup 1.0000x reference)
//
#include <hip/hip_runtime.h>
#include <hip/hip_bf16.h>

#define T_ 8
#define H_ 96
#define W_ 160
#define C_ 256
#define F_ 256

typedef __bf16 bf16_t;
typedef __bf16 bf16x4 __attribute__((ext_vector_type(4)));
typedef __bf16 bf16x8 __attribute__((ext_vector_type(8)));
typedef float  f32x4  __attribute__((ext_vector_type(4)));

// ---------------- pass 0: WpT[f][c] = bf16(Wp[c][f]) ----------------
__global__ void wp_transpose_kernel(const float* __restrict__ Wp,
                                    bf16_t* __restrict__ WpT) {
    int f = blockIdx.x;   // 0..255
    int c = threadIdx.x;  // 0..255
    WpT[f * C_ + c] = (bf16_t)Wp[c * F_ + f];
}

// ---------------- fused: dw 3x3x3 (fp32 in LDS) -> bf16 A -> MFMA(B=WpT) -> ReLU ----
// Block tile: BM=64 rows = (t:0..7) x (w-octet), h fixed.  BN=256 (full F). BK=32.
// 256 threads (4 waves, each wave owns 16 rows x 256 cols).  LDS 58.9 KB -> 2 blocks/CU.
__global__ __launch_bounds__(256, 2) void fused_kernel(
    const float* __restrict__ x, const float* __restrict__ Wd,
    const bf16_t* __restrict__ WpT, float* __restrict__ out)
{
    // pt = (tE*3 + hE)*10 + wE ; tE in 0..9 (t halo, planes 0/9 stay zero),
    // hE in 0..2 (h-1..h+1), wE in 0..9 (w0-1..w0+8)
    __shared__ float  xs[300 * 32];        // [pt][32ch] fp32           38400 B
    __shared__ bf16_t As[4 * 64 * 8];      // [kg][row][8ch] bf16        4096 B
    __shared__ bf16_t Bs[4 * 256 * 8];     // [kg][f][8ch]   bf16       16384 B

    const int b   = blockIdx.x;
    const int h   = b / 20;            // 0..95
    const int w0  = (b % 20) * 8;      // w-octet base
    const int tid = threadIdx.x;

    // depthwise-phase roles
    const int cq = tid & 7;            // ch-quad within 32-ch chunk
    const int sg = tid >> 3;           // 0..31
    const int tt = sg >> 2;            // 0..7  (t)
    const int wp = sg & 3;             // w-pair: outputs w-in-tile {2wp, 2wp+1}

    // mfma-phase roles
    const int wrg  = tid >> 6;         // wave id: rows wrg*16..+15
    const int lane = tid & 63;
    const int r16  = lane & 15;
    const int kg   = lane >> 4;        // k-octet

    f32x4 acc[16] = {};                // 16 n-frags x 4 rows

    f32x4* xs4 = (f32x4*)xs;

    for (int kc = 0; kc < 8; ++kc) {
        __syncthreads();               // prev-chunk MFMA reads done before overwrite
        const int c0 = kc * 32;

        // ---- stage x chunk (fp32, zero halos; every slot rewritten -> no staleness) ----
        for (int i = tid; i < 2400; i += 256) {      // 300 pts x 8 c-quads
            int pt = i >> 3, seg = i & 7;
            int tE = pt / 30, rem = pt - tE * 30;
            int hE = rem / 10, wE = rem - hE * 10;
            int hg = h + hE - 1, wg = w0 + wE - 1;
            f32x4 v = {};
            if (tE >= 1 && tE <= 8 && (unsigned)hg < (unsigned)H_ && (unsigned)wg < (unsigned)W_) {
                v = *(const f32x4*)&x[(((tE - 1) * H_ + hg) * W_ + wg) * C_ + c0 + seg * 4];
            }
            xs4[i] = v;
        }
        // ---- stage B chunk: Bs[kg][f][8] <- WpT[f][c0 + kg*8 ..] ----
        for (int i = tid; i < 1024; i += 256) {
            int bkg = i >> 8, f = i & 255;
            *(bf16x8*)&Bs[i * 8] = *(const bf16x8*)&WpT[f * C_ + c0 + bkg * 8];
        }
        __syncthreads();

        // ---- depthwise 3x3x3 from LDS (fp32), 2 w-outputs x 4 ch per thread ----
        f32x4 a0 = {}, a1 = {};
#pragma unroll
        for (int dt = -1; dt <= 1; ++dt) {
            const int tE = tt + dt + 1;            // 0..9, planes 0/9 are zeros
            f32x4 wv[3][3];
#pragma unroll
            for (int dh = 0; dh < 3; ++dh)
#pragma unroll
                for (int kw = 0; kw < 3; ++kw)
                    wv[dh][kw] = *(const f32x4*)&Wd[(((dt + 1) * 3 + dh) * 3 + kw) * C_ + c0 + cq * 4];
#pragma unroll
            for (int dh = 0; dh < 3; ++dh) {
                const int pt0 = (tE * 3 + dh) * 10 + 2 * wp;
                f32x4 xv0 = xs4[(pt0 + 0) * 8 + cq];
                f32x4 xv1 = xs4[(pt0 + 1) * 8 + cq];
                f32x4 xv2 = xs4[(pt0 + 2) * 8 + cq];
                f32x4 xv3 = xs4[(pt0 + 3) * 8 + cq];
                a0 += xv0 * wv[dh][0];  a1 += xv1 * wv[dh][0];
                a0 += xv1 * wv[dh][1];  a1 += xv2 * wv[dh][1];
                a0 += xv2 * wv[dh][2];  a1 += xv3 * wv[dh][2];
            }
        }
        // write A-tile: rows r = tt*8 + 2wp + j, subtiled [kg=cq>>1][row][(cq&1)*4..]
        {
            const int r0 = tt * 8 + 2 * wp;
            bf16x4 o0, o1;
#pragma unroll
            for (int q = 0; q < 4; ++q) { o0[q] = (bf16_t)a0[q]; o1[q] = (bf16_t)a1[q]; }
            const int base = (cq >> 1) * 512 + (cq & 1) * 4;
            *(bf16x4*)&As[base + r0 * 8]       = o0;
            *(bf16x4*)&As[base + (r0 + 1) * 8] = o1;
        }
        __syncthreads();

        // ---- MFMA: 1 A-frag, 16 B-frags, 16 mfma (K=32 == one k-step) ----
        bf16x8 af = *(const bf16x8*)&As[kg * 512 + (wrg * 16 + r16) * 8];
#pragma unroll
        for (int n = 0; n < 16; ++n) {
            bf16x8 bfr = *(const bf16x8*)&Bs[kg * 2048 + (n * 16 + r16) * 8];
            acc[n] = __builtin_amdgcn_mfma_f32_16x16x32_bf16(af, bfr, acc[n], 0, 0, 0);
        }
    }

    // ---- epilogue: ReLU + fp32 store.  D layout: row=(l>>4)*4+rr, col=l&15 ----
#pragma unroll
    for (int n = 0; n < 16; ++n)
#pragma unroll
        for (int rr = 0; rr < 4; ++rr) {
            int r = wrg * 16 + kg * 4 + rr;     // row in tile
            int t = r >> 3, wt = r & 7;
            int m = (t * H_ + h) * W_ + (w0 + wt);
            float v = acc[n][rr];
            out[m * F_ + n * 16 + r16] = v > 0.f ? v : 0.f;
        }
}

extern "C" void kernel_launch(void* const* d_in, const int* in_sizes, int n_in,
                              void* d_out, int out_size, void* d_ws, size_t ws_size,
                              hipStream_t stream) {
    const float* x  = (const float*)d_in[0];
    const float* Wd = (const float*)d_in[1];
    const float* Wp = (const float*)d_in[2];
    float* out = (float*)d_out;

    bf16_t* WpT = (bf16_t*)d_ws;   // F_*C_ bf16 = 131072 B

    wp_transpose_kernel<<<F_, C_, 0, stream>>>(Wp, WpT);
    fused_kernel<<<H_ * (W_ / 8), 256, 0, stream>>>(x, Wd, WpT, out);
}

// Round 3
// 135.680 us; speedup vs baseline: 1.6409x; 1.6409x over previous
//
#include <hip/hip_runtime.h>
#include <hip/hip_bf16.h>

#define T_ 8
#define H_ 96
#define W_ 160
#define C_ 256
#define F_ 256
#define M_ (T_ * H_ * W_)   // 122880

typedef __bf16 bf16_t;
typedef __bf16 bf16x2 __attribute__((ext_vector_type(2)));
typedef __bf16 bf16x8 __attribute__((ext_vector_type(8)));
typedef float  f32x2  __attribute__((ext_vector_type(2)));
typedef float  f32x4  __attribute__((ext_vector_type(4)));

// ---------------- pass 0: WpT[f][c] = bf16(Wp[c][f]) ----------------
__global__ void wp_transpose_kernel(const float* __restrict__ Wp,
                                    bf16_t* __restrict__ WpT) {
    int f = blockIdx.x;   // 0..255
    int c = threadIdx.x;  // 0..255
    WpT[f * C_ + c] = (bf16_t)Wp[c * F_ + f];
}

// ---------------- pass 1: depthwise 3x3x3 conv, fp32 -> bf16 ----------------
// block = (h-pair, w-pair); thread = (channel-pair, w-in-pair).
// f32x2 loads (8B/lane, 512B/wave) halve instruction count vs round-1 and
// double per-thread ILP; all 8 T outputs stay in registers.
__global__ __launch_bounds__(256, 4) void dw_conv_kernel(const float* __restrict__ x,
                                                         const float* __restrict__ Wd,
                                                         bf16_t* __restrict__ dw) {
    int b   = blockIdx.x;            // 0..3839  (48 h-pairs * 80 w-pairs)
    int h2  = b / (W_ / 2);
    int wq  = b % (W_ / 2);
    int h0  = h2 * 2;
    int tid = threadIdx.x;
    int c   = (tid & 127) * 2;       // channel pair
    int w   = wq * 2 + (tid >> 7);   // wave-uniform (waves 0,1 -> w0; 2,3 -> w0+1)

    f32x2 wreg[27];
#pragma unroll
    for (int k = 0; k < 27; ++k) wreg[k] = *(const f32x2*)&Wd[k * C_ + c];

    f32x2 acc[2][8] = {};

    const int tstride = H_ * W_ * C_;

#pragma unroll
    for (int dh = -1; dh <= 2; ++dh) {
        int hh = h0 + dh;
        if (hh < 0 || hh >= H_) continue;      // wave-uniform
#pragma unroll
        for (int dwi = -1; dwi <= 1; ++dwi) {
            int ww = w + dwi;
            if (ww < 0 || ww >= W_) continue;  // wave-uniform
            int kw = dwi + 1;
            const float* px = x + (hh * W_ + ww) * C_ + c;
#pragma unroll
            for (int tt = 0; tt < 8; ++tt) {
                f32x2 v = *(const f32x2*)&px[tt * tstride];
#pragma unroll
                for (int j = 0; j < 2; ++j) {
                    int kh = dh + 1 - j;
                    if (kh < 0 || kh > 2) continue;   // compile-time
#pragma unroll
                    for (int kt = 0; kt < 3; ++kt) {
                        int to = tt + 1 - kt;
                        if (to < 0 || to >= 8) continue;  // compile-time
                        acc[j][to] += v * wreg[(kt * 3 + kh) * 3 + kw];
                    }
                }
            }
        }
    }

#pragma unroll
    for (int j = 0; j < 2; ++j)
#pragma unroll
        for (int tt = 0; tt < 8; ++tt) {
            bf16x2 o;
            o[0] = (bf16_t)acc[j][tt][0];
            o[1] = (bf16_t)acc[j][tt][1];
            *(bf16x2*)&dw[((tt * H_ + (h0 + j)) * W_ + w) * C_ + c] = o;
        }
}

// ---------------- pass 2: GEMM [M,256]x[256,256] bf16 MFMA + ReLU ----------------
#define BM 128
#define BN 128
#define BK 32
#define LDSTR 40  // 32 + 8 pad: fragment ds_read_b128 2-way (free) instead of 8-way

__global__ __launch_bounds__(256) void gemm_kernel(const bf16_t* __restrict__ A,   // dw  [M][C]
                                                   const bf16_t* __restrict__ Bt,  // WpT [F][C] (n-major)
                                                   float* __restrict__ out) {      // [M][F]
    __shared__ __align__(16) bf16_t As[BM * LDSTR];
    __shared__ __align__(16) bf16_t Bs[BN * LDSTR];

    int m0   = blockIdx.x * BM;
    int n0   = blockIdx.y * BN;
    int tid  = threadIdx.x;
    int lane = tid & 63;
    int wid  = tid >> 6;
    int wr   = wid >> 1;   // 0..1
    int wc   = wid & 1;    // 0..1
    int r16  = lane & 15;
    int kg   = lane >> 4;  // 0..3

    f32x4 acc[4][4] = {};

    for (int k0 = 0; k0 < C_; k0 += BK) {
        __syncthreads();
#pragma unroll
        for (int it = 0; it < 2; ++it) {
            int slot = tid + it * 256;       // 0..511
            int row  = slot >> 2;            // 0..127
            int seg  = slot & 3;             // 0..3 (8 bf16 each)
            uint4 va = *(const uint4*)&A[(long)(m0 + row) * C_ + k0 + seg * 8];
            *(uint4*)&As[row * LDSTR + seg * 8] = va;
            uint4 vb = *(const uint4*)&Bt[(n0 + row) * C_ + k0 + seg * 8];
            *(uint4*)&Bs[row * LDSTR + seg * 8] = vb;
        }
        __syncthreads();

        bf16x8 af[4], bfr[4];
#pragma unroll
        for (int m = 0; m < 4; ++m)
            af[m] = *(const bf16x8*)&As[(wr * 64 + m * 16 + r16) * LDSTR + kg * 8];
#pragma unroll
        for (int n = 0; n < 4; ++n)
            bfr[n] = *(const bf16x8*)&Bs[(wc * 64 + n * 16 + r16) * LDSTR + kg * 8];

#pragma unroll
        for (int m = 0; m < 4; ++m)
#pragma unroll
            for (int n = 0; n < 4; ++n)
                acc[m][n] = __builtin_amdgcn_mfma_f32_16x16x32_bf16(af[m], bfr[n], acc[m][n], 0, 0, 0);
    }

    // epilogue: ReLU + fp32 store.  D layout: row=(l>>4)*4+r, col=l&15
    int rbase = m0 + wr * 64 + kg * 4;
    int cbase = n0 + wc * 64 + r16;
#pragma unroll
    for (int m = 0; m < 4; ++m)
#pragma unroll
        for (int n = 0; n < 4; ++n)
#pragma unroll
            for (int r = 0; r < 4; ++r) {
                float v = acc[m][n][r];
                v = v > 0.f ? v : 0.f;
                out[(long)(rbase + m * 16 + r) * F_ + cbase + n * 16] = v;
            }
}

extern "C" void kernel_launch(void* const* d_in, const int* in_sizes, int n_in,
                              void* d_out, int out_size, void* d_ws, size_t ws_size,
                              hipStream_t stream) {
    const float* x  = (const float*)d_in[0];
    const float* Wd = (const float*)d_in[1];
    const float* Wp = (const float*)d_in[2];
    float* out = (float*)d_out;

    bf16_t* dw  = (bf16_t*)d_ws;                                  // M_*C_ bf16 = 62,914,560 B
    bf16_t* WpT = (bf16_t*)((char*)d_ws + (size_t)M_ * C_ * 2);   // + 131,072 B

    wp_transpose_kernel<<<F_, C_, 0, stream>>>(Wp, WpT);
    dw_conv_kernel<<<(H_ / 2) * (W_ / 2), 256, 0, stream>>>(x, Wd, dw);
    gemm_kernel<<<dim3(M_ / BM, F_ / BN), 256, 0, stream>>>(dw, WpT, out);
}